// Round 1
// baseline (1043.254 us; speedup 1.0000x reference)
//
#include <hip/hip_runtime.h>
#include <hip/hip_bf16.h>

typedef unsigned short u16;
typedef unsigned int u32;
typedef __bf16 v8bf __attribute__((ext_vector_type(8)));
typedef float v4f __attribute__((ext_vector_type(4)));

#define B_ROWS 1024
#define D_DIM  512
#define C_CLS  100000
#define SCALE_F 30.0f
#define MARGIN_F 0.4f

// pack two fp32 -> two bf16 (RNE, no NaN handling needed: inputs are finite/small)
__device__ __forceinline__ u32 rne2(float a, float b) {
    u32 ua = __float_as_uint(a), ub = __float_as_uint(b);
    ua = ua + 0x7FFFu + ((ua >> 16) & 1u);
    ub = ub + 0x7FFFu + ((ub >> 16) & 1u);
    return (ua >> 16) | (ub & 0xFFFF0000u);
}

// ---------------- prep x: row-normalize, convert to bf16, zero SUM ----------------
__global__ __launch_bounds__(64) void prep_x(const float* __restrict__ x,
                                             u16* __restrict__ XB,
                                             float* __restrict__ SUM) {
    const int row = blockIdx.x;
    const int lane = threadIdx.x;
    const float4* xr = (const float4*)(x + (size_t)row * D_DIM);
    float4 a = xr[lane];
    float4 b = xr[lane + 64];
    float s = a.x*a.x + a.y*a.y + a.z*a.z + a.w*a.w
            + b.x*b.x + b.y*b.y + b.z*b.z + b.w*b.w;
    #pragma unroll
    for (int m = 32; m > 0; m >>= 1) s += __shfl_xor(s, m, 64);
    const float inv = 1.0f / fmaxf(sqrtf(s), 1e-12f);
    uint2 pa, pb;
    pa.x = rne2(a.x*inv, a.y*inv); pa.y = rne2(a.z*inv, a.w*inv);
    pb.x = rne2(b.x*inv, b.y*inv); pb.y = rne2(b.z*inv, b.w*inv);
    *(uint2*)(XB + (size_t)row * D_DIM + lane*4)       = pa;
    *(uint2*)(XB + (size_t)row * D_DIM + 256 + lane*4) = pb;
    if (lane == 0) SUM[row] = 0.0f;
}

// ---------------- prep w: row norms; WB_MODE also writes normalized bf16 ----------------
template<bool WB_MODE>
__global__ __launch_bounds__(256) void prep_w(const float* __restrict__ w,
                                              u16* __restrict__ WB,
                                              float* __restrict__ invnw) {
    const int row = blockIdx.x * 4 + (threadIdx.x >> 6);
    const int lane = threadIdx.x & 63;
    const float4* wr = (const float4*)(w + (size_t)row * D_DIM);
    float4 a = wr[lane];
    float4 b = wr[lane + 64];
    float s = a.x*a.x + a.y*a.y + a.z*a.z + a.w*a.w
            + b.x*b.x + b.y*b.y + b.z*b.z + b.w*b.w;
    #pragma unroll
    for (int m = 32; m > 0; m >>= 1) s += __shfl_xor(s, m, 64);
    const float inv = 1.0f / fmaxf(sqrtf(s), 1e-12f);
    if (WB_MODE) {
        uint2 pa, pb;
        pa.x = rne2(a.x*inv, a.y*inv); pa.y = rne2(a.z*inv, a.w*inv);
        pb.x = rne2(b.x*inv, b.y*inv); pb.y = rne2(b.z*inv, b.w*inv);
        *(uint2*)(WB + (size_t)row * D_DIM + lane*4)       = pa;
        *(uint2*)(WB + (size_t)row * D_DIM + 256 + lane*4) = pb;
    } else {
        if (lane == 0) invnw[row] = inv;
    }
}

// ---------------- GEMM: cosine = XBn @ WBn^T, fused exp-sum epilogue ----------------
// tile 256(M) x 128(N), BK=64, 512 threads = 8 waves (4 along M x 2 along N),
// each wave 64x64 via 4x4 grid of 16x16x32 bf16 MFMA.
template<bool USE_WB>
__global__ __launch_bounds__(512, 4) void gemm_k(
        const u16* __restrict__ XB, const u16* __restrict__ WB,
        const float* __restrict__ W, const float* __restrict__ invnw,
        float* __restrict__ out, float* __restrict__ SUM) {
    __shared__ u16 sA[256][72];   // 64 bf16 + 8 pad (16B) per row
    __shared__ u16 sB[128][72];

    const int tid = threadIdx.x;
    const int m0 = blockIdx.x * 256;
    const int n0 = blockIdx.y * 128;
    const int lane = tid & 63;
    const int wv = tid >> 6;
    const int wm = wv & 3;        // 0..3 along M
    const int wn = wv >> 2;       // 0..1 along N
    const int col = lane & 15;
    const int quad = lane >> 4;

    v4f acc[4][4];
    #pragma unroll
    for (int mi = 0; mi < 4; ++mi)
        #pragma unroll
        for (int ni = 0; ni < 4; ++ni)
            acc[mi][ni] = (v4f){0.f, 0.f, 0.f, 0.f};

    for (int kt = 0; kt < 8; ++kt) {
        const int k0 = kt * 64;
        // ---- global loads (A: 4x16B bf16 chunks, B: 2 chunks) ----
        uint4 av[4];
        #pragma unroll
        for (int i = 0; i < 4; ++i) {
            int ch = tid + 512*i; int r = ch >> 3, c = ch & 7;
            av[i] = *(const uint4*)(XB + (size_t)(m0 + r) * D_DIM + k0 + c*8);
        }
        uint4 bv[2];
        if (USE_WB) {
            #pragma unroll
            for (int i = 0; i < 2; ++i) {
                int ch = tid + 512*i; int r = ch >> 3, c = ch & 7;
                int gc = n0 + r;
                bv[i] = (gc < C_CLS)
                      ? *(const uint4*)(WB + (size_t)gc * D_DIM + k0 + c*8)
                      : make_uint4(0u, 0u, 0u, 0u);
            }
        } else {
            #pragma unroll
            for (int i = 0; i < 2; ++i) {
                int ch = tid + 512*i; int r = ch >> 3, c = ch & 7;
                int gc = n0 + r;
                float4 f0, f1; float inv;
                if (gc < C_CLS) {
                    const float* p = W + (size_t)gc * D_DIM + k0 + c*8;
                    f0 = *(const float4*)p;
                    f1 = *(const float4*)(p + 4);
                    inv = invnw[gc];
                } else {
                    f0 = make_float4(0.f,0.f,0.f,0.f);
                    f1 = make_float4(0.f,0.f,0.f,0.f);
                    inv = 0.f;
                }
                uint4 pk;
                pk.x = rne2(f0.x*inv, f0.y*inv); pk.y = rne2(f0.z*inv, f0.w*inv);
                pk.z = rne2(f1.x*inv, f1.y*inv); pk.w = rne2(f1.z*inv, f1.w*inv);
                bv[i] = pk;
            }
        }
        __syncthreads();   // previous iteration's LDS reads done
        #pragma unroll
        for (int i = 0; i < 4; ++i) {
            int ch = tid + 512*i; int r = ch >> 3, c = ch & 7;
            *(uint4*)&sA[r][c*8] = av[i];
        }
        #pragma unroll
        for (int i = 0; i < 2; ++i) {
            int ch = tid + 512*i; int r = ch >> 3, c = ch & 7;
            *(uint4*)&sB[r][c*8] = bv[i];
        }
        __syncthreads();

        // ---- MFMA over BK=64 (two K=32 steps) ----
        #pragma unroll
        for (int kk = 0; kk < 64; kk += 32) {
            v8bf af[4], bfv[4];
            #pragma unroll
            for (int mi = 0; mi < 4; ++mi)
                af[mi] = *(const v8bf*)&sA[wm*64 + mi*16 + col][kk + quad*8];
            #pragma unroll
            for (int ni = 0; ni < 4; ++ni)
                bfv[ni] = *(const v8bf*)&sB[wn*64 + ni*16 + col][kk + quad*8];
            #pragma unroll
            for (int mi = 0; mi < 4; ++mi)
                #pragma unroll
                for (int ni = 0; ni < 4; ++ni)
                    acc[mi][ni] = __builtin_amdgcn_mfma_f32_16x16x32_bf16(
                        af[mi], bfv[ni], acc[mi][ni], 0, 0, 0);
        }
    }

    // ---- epilogue: store cosine + per-row sum of exp(30*cos) ----
    const float e2s = 43.2808512266689f;   // 30 * log2(e)
    float* outc = out + 1;
    #pragma unroll
    for (int mi = 0; mi < 4; ++mi) {
        #pragma unroll
        for (int r = 0; r < 4; ++r) {
            const int gm = m0 + wm*64 + mi*16 + quad*4 + r;  // M index (row)
            float rs = 0.f;
            #pragma unroll
            for (int ni = 0; ni < 4; ++ni) {
                const int gc = n0 + wn*64 + ni*16 + col;     // N index (col)
                const float cv = acc[mi][ni][r];
                if (gc < C_CLS) {
                    outc[(long)gm * C_CLS + gc] = cv;
                    rs += exp2f(cv * e2s);
                }
            }
            rs += __shfl_xor(rs, 1);
            rs += __shfl_xor(rs, 2);
            rs += __shfl_xor(rs, 4);
            rs += __shfl_xor(rs, 8);
            if (col == 0) atomicAdd(&SUM[gm], rs);
        }
    }
}

// ---------------- final loss ----------------
__global__ __launch_bounds__(256) void loss_k(const float* __restrict__ out,
                                              const int* __restrict__ label,
                                              const float* __restrict__ SUM,
                                              float* __restrict__ out0) {
    __shared__ float red[256];
    const int t = threadIdx.x;
    float accv = 0.f;
    #pragma unroll
    for (int i = 0; i < 4; ++i) {
        const int b = t + 256*i;
        const float tgt = out[1 + (long)b * C_CLS + label[b]];
        const float num = SCALE_F * (tgt - MARGIN_F);
        const float ex_t = expf(SCALE_F * tgt);
        const float denom = expf(num) + (SUM[b] - ex_t);
        accv += num - logf(denom);
    }
    red[t] = accv;
    __syncthreads();
    for (int s = 128; s > 0; s >>= 1) {
        if (t < s) red[t] += red[t + s];
        __syncthreads();
    }
    if (t == 0) out0[0] = -red[0] / (float)B_ROWS;
}

extern "C" void kernel_launch(void* const* d_in, const int* in_sizes, int n_in,
                              void* d_out, int out_size, void* d_ws, size_t ws_size,
                              hipStream_t stream) {
    const float* x     = (const float*)d_in[0];
    const int*   label = (const int*)d_in[1];
    const float* w     = (const float*)d_in[2];
    float* out = (float*)d_out;
    char*  ws  = (char*)d_ws;

    float* SUM   = (float*)ws;                       // 4 KB
    float* invnw = (float*)(ws + 4096);              // 400 KB
    u16*   XB    = (u16*)(ws + 512*1024);            // 1 MB
    u16*   WB    = (u16*)(ws + 2*1024*1024);         // 102.4 MB (optional)
    const size_t wb_need = (size_t)2*1024*1024 + (size_t)C_CLS * D_DIM * 2;
    const bool use_wb = ws_size >= wb_need;

    prep_x<<<dim3(B_ROWS), dim3(64), 0, stream>>>(x, XB, SUM);

    const dim3 ggrid(B_ROWS / 256, (C_CLS + 127) / 128);  // (4, 782), M fastest
    if (use_wb) {
        prep_w<true><<<dim3(C_CLS / 4), dim3(256), 0, stream>>>(w, WB, invnw);
        gemm_k<true><<<ggrid, dim3(512), 0, stream>>>(XB, WB, nullptr, nullptr, out, SUM);
    } else {
        prep_w<false><<<dim3(C_CLS / 4), dim3(256), 0, stream>>>(w, WB, invnw);
        gemm_k<false><<<ggrid, dim3(512), 0, stream>>>(XB, nullptr, w, invnw, out, SUM);
    }
    loss_k<<<dim3(1), dim3(256), 0, stream>>>(out, label, SUM, out);
}

// Round 2
// 965.923 us; speedup vs baseline: 1.0801x; 1.0801x over previous
//
#include <hip/hip_runtime.h>
#include <hip/hip_bf16.h>

typedef unsigned short u16;
typedef unsigned int u32;
typedef __bf16 v8bf __attribute__((ext_vector_type(8)));
typedef float v4f __attribute__((ext_vector_type(4)));

#define B_ROWS 1024
#define D_DIM  512
#define C_CLS  100000
#define SCALE_F 30.0f
#define MARGIN_F 0.4f

// pack two fp32 -> two bf16 (RNE)
__device__ __forceinline__ u32 rne2(float a, float b) {
    u32 ua = __float_as_uint(a), ub = __float_as_uint(b);
    ua = ua + 0x7FFFu + ((ua >> 16) & 1u);
    ub = ub + 0x7FFFu + ((ub >> 16) & 1u);
    return (ua >> 16) | (ub & 0xFFFF0000u);
}

// forced 16B store at dword-aligned (not 16B-aligned) address; CDNA global ops
// need only dword alignment. Needed because out+1 shifts rows by 4B.
__device__ __forceinline__ void store_f4_unaligned(float* p, v4f v) {
    asm volatile("global_store_dwordx4 %0, %1, off" :: "v"(p), "v"(v) : "memory");
}

// ---------------- prep x: row-normalize, convert to bf16, zero SUM ----------------
__global__ __launch_bounds__(64) void prep_x(const float* __restrict__ x,
                                             u16* __restrict__ XB,
                                             float* __restrict__ SUM) {
    const int row = blockIdx.x;
    const int lane = threadIdx.x;
    const float4* xr = (const float4*)(x + (size_t)row * D_DIM);
    float4 a = xr[lane];
    float4 b = xr[lane + 64];
    float s = a.x*a.x + a.y*a.y + a.z*a.z + a.w*a.w
            + b.x*b.x + b.y*b.y + b.z*b.z + b.w*b.w;
    #pragma unroll
    for (int m = 32; m > 0; m >>= 1) s += __shfl_xor(s, m, 64);
    const float inv = 1.0f / fmaxf(sqrtf(s), 1e-12f);
    uint2 pa, pb;
    pa.x = rne2(a.x*inv, a.y*inv); pa.y = rne2(a.z*inv, a.w*inv);
    pb.x = rne2(b.x*inv, b.y*inv); pb.y = rne2(b.z*inv, b.w*inv);
    *(uint2*)(XB + (size_t)row * D_DIM + lane*4)       = pa;
    *(uint2*)(XB + (size_t)row * D_DIM + 256 + lane*4) = pb;
    if (lane == 0) SUM[row] = 0.0f;
}

// ---------------- prep w ----------------
template<bool WB_MODE>
__global__ __launch_bounds__(256) void prep_w(const float* __restrict__ w,
                                              u16* __restrict__ WB,
                                              float* __restrict__ invnw) {
    const int row = blockIdx.x * 4 + (threadIdx.x >> 6);
    const int lane = threadIdx.x & 63;
    const float4* wr = (const float4*)(w + (size_t)row * D_DIM);
    float4 a = wr[lane];
    float4 b = wr[lane + 64];
    float s = a.x*a.x + a.y*a.y + a.z*a.z + a.w*a.w
            + b.x*b.x + b.y*b.y + b.z*b.z + b.w*b.w;
    #pragma unroll
    for (int m = 32; m > 0; m >>= 1) s += __shfl_xor(s, m, 64);
    const float inv = 1.0f / fmaxf(sqrtf(s), 1e-12f);
    if (WB_MODE) {
        uint2 pa, pb;
        pa.x = rne2(a.x*inv, a.y*inv); pa.y = rne2(a.z*inv, a.w*inv);
        pb.x = rne2(b.x*inv, b.y*inv); pb.y = rne2(b.z*inv, b.w*inv);
        *(uint2*)(WB + (size_t)row * D_DIM + lane*4)       = pa;
        *(uint2*)(WB + (size_t)row * D_DIM + 256 + lane*4) = pb;
    } else {
        if (lane == 0) invnw[row] = inv;
    }
}

// ---------------- GEMM: cosine = XBn @ WBn^T, fused exp-sum epilogue ----------------
// tile 256(M) x 128(N), BK=64, 512 threads = 8 waves (4 along M x 2 along N).
template<bool USE_WB>
__global__ __launch_bounds__(512, 4) void gemm_k(
        const u16* __restrict__ XB, const u16* __restrict__ WB,
        const float* __restrict__ W, const float* __restrict__ invnw,
        float* __restrict__ out, float* __restrict__ SUM) {
    __shared__ __align__(16) char smem[55296];
    u16 (*sA)[72] = (u16(*)[72])smem;             // 256*72*2 = 36864
    u16 (*sB)[72] = (u16(*)[72])(smem + 36864);   // 128*72*2 = 18432
    float* sC = (float*)smem;                     // epilogue: 64*132*4 = 33792

    const int tid = threadIdx.x;
    const int m0 = blockIdx.x * 256;
    const int n0 = blockIdx.y * 128;
    const int lane = tid & 63;
    const int wv = tid >> 6;
    const int wm = wv & 3;        // 0..3 along M
    const int wn = wv >> 2;       // 0..1 along N
    const int col = lane & 15;
    const int quad = lane >> 4;

    v4f acc[4][4];
    #pragma unroll
    for (int mi = 0; mi < 4; ++mi)
        #pragma unroll
        for (int ni = 0; ni < 4; ++ni)
            acc[mi][ni] = (v4f){0.f, 0.f, 0.f, 0.f};

    for (int kt = 0; kt < 8; ++kt) {
        const int k0 = kt * 64;
        uint4 av[4];
        #pragma unroll
        for (int i = 0; i < 4; ++i) {
            int ch = tid + 512*i; int r = ch >> 3, c = ch & 7;
            av[i] = *(const uint4*)(XB + (size_t)(m0 + r) * D_DIM + k0 + c*8);
        }
        uint4 bv[2];
        if (USE_WB) {
            #pragma unroll
            for (int i = 0; i < 2; ++i) {
                int ch = tid + 512*i; int r = ch >> 3, c = ch & 7;
                int gc = n0 + r;
                bv[i] = (gc < C_CLS)
                      ? *(const uint4*)(WB + (size_t)gc * D_DIM + k0 + c*8)
                      : make_uint4(0u, 0u, 0u, 0u);
            }
        } else {
            #pragma unroll
            for (int i = 0; i < 2; ++i) {
                int ch = tid + 512*i; int r = ch >> 3, c = ch & 7;
                int gc = n0 + r;
                float4 f0, f1; float inv;
                if (gc < C_CLS) {
                    const float* p = W + (size_t)gc * D_DIM + k0 + c*8;
                    f0 = *(const float4*)p;
                    f1 = *(const float4*)(p + 4);
                    inv = invnw[gc];
                } else {
                    f0 = make_float4(0.f,0.f,0.f,0.f);
                    f1 = make_float4(0.f,0.f,0.f,0.f);
                    inv = 0.f;
                }
                uint4 pk;
                pk.x = rne2(f0.x*inv, f0.y*inv); pk.y = rne2(f0.z*inv, f0.w*inv);
                pk.z = rne2(f1.x*inv, f1.y*inv); pk.w = rne2(f1.z*inv, f1.w*inv);
                bv[i] = pk;
            }
        }
        __syncthreads();
        #pragma unroll
        for (int i = 0; i < 4; ++i) {
            int ch = tid + 512*i; int r = ch >> 3, c = ch & 7;
            *(uint4*)&sA[r][c*8] = av[i];
        }
        #pragma unroll
        for (int i = 0; i < 2; ++i) {
            int ch = tid + 512*i; int r = ch >> 3, c = ch & 7;
            *(uint4*)&sB[r][c*8] = bv[i];
        }
        __syncthreads();

        #pragma unroll
        for (int kk = 0; kk < 64; kk += 32) {
            v8bf af[4], bfv[4];
            #pragma unroll
            for (int mi = 0; mi < 4; ++mi)
                af[mi] = *(const v8bf*)&sA[wm*64 + mi*16 + col][kk + quad*8];
            #pragma unroll
            for (int ni = 0; ni < 4; ++ni)
                bfv[ni] = *(const v8bf*)&sB[wn*64 + ni*16 + col][kk + quad*8];
            #pragma unroll
            for (int mi = 0; mi < 4; ++mi)
                #pragma unroll
                for (int ni = 0; ni < 4; ++ni)
                    acc[mi][ni] = __builtin_amdgcn_mfma_f32_16x16x32_bf16(
                        af[mi], bfv[ni], acc[mi][ni], 0, 0, 0);
        }
    }

    // ---- epilogue: LDS bounce -> contiguous 512B/row stores + per-row exp-sum ----
    const float e2s = 43.2808512266689f;   // 30 * log2(e)
    float* outc = out + 1;
    __syncthreads();   // all MFMA LDS reads done before overwriting smem
    #pragma unroll
    for (int mi = 0; mi < 4; ++mi) {
        // deposit this mi-chunk (64 rows x 128 cols) into LDS, stride 132 (2-way conflicts only)
        #pragma unroll
        for (int ni = 0; ni < 4; ++ni)
            #pragma unroll
            for (int r = 0; r < 4; ++r)
                sC[(wm*16 + quad*4 + r)*132 + wn*64 + ni*16 + col] = acc[mi][ni][r];
        __syncthreads();
        #pragma unroll
        for (int j = 0; j < 4; ++j) {
            const int li = tid + 512*j;
            const int lr = li >> 5;        // 0..63: local row
            const int sl = li & 31;        // 32 lanes cover a 128-col row
            v4f v = *(const v4f*)&sC[lr*132 + sl*4];
            const int gm = m0 + (lr >> 4)*64 + mi*16 + (lr & 15);
            const int gc = n0 + sl*4;
            float rs = 0.f;
            if (gc + 4 <= C_CLS) {
                store_f4_unaligned(outc + (size_t)gm * C_CLS + gc, v);
                rs = exp2f(v[0]*e2s) + exp2f(v[1]*e2s)
                   + exp2f(v[2]*e2s) + exp2f(v[3]*e2s);
            }
            rs += __shfl_xor(rs, 1);
            rs += __shfl_xor(rs, 2);
            rs += __shfl_xor(rs, 4);
            rs += __shfl_xor(rs, 8);
            rs += __shfl_xor(rs, 16);
            if (sl == 0) atomicAdd(&SUM[gm], rs);
        }
        __syncthreads();
    }
}

// ---------------- final loss: one thread per batch row ----------------
__global__ __launch_bounds__(1024) void loss_k(const float* __restrict__ out,
                                               const int* __restrict__ label,
                                               const float* __restrict__ SUM,
                                               float* __restrict__ out0) {
    __shared__ float red[1024];
    const int t = threadIdx.x;
    const float tgt = out[1 + (size_t)t * C_CLS + label[t]];
    const float num = SCALE_F * (tgt - MARGIN_F);
    const float ex_t = expf(SCALE_F * tgt);
    const float denom = expf(num) + (SUM[t] - ex_t);
    red[t] = num - logf(denom);
    __syncthreads();
    for (int s = 512; s > 0; s >>= 1) {
        if (t < s) red[t] += red[t + s];
        __syncthreads();
    }
    if (t == 0) out0[0] = -red[0] / (float)B_ROWS;
}

extern "C" void kernel_launch(void* const* d_in, const int* in_sizes, int n_in,
                              void* d_out, int out_size, void* d_ws, size_t ws_size,
                              hipStream_t stream) {
    const float* x     = (const float*)d_in[0];
    const int*   label = (const int*)d_in[1];
    const float* w     = (const float*)d_in[2];
    float* out = (float*)d_out;
    char*  ws  = (char*)d_ws;

    float* SUM   = (float*)ws;                       // 4 KB
    float* invnw = (float*)(ws + 4096);              // 400 KB
    u16*   XB    = (u16*)(ws + 512*1024);            // 1 MB
    u16*   WB    = (u16*)(ws + 2*1024*1024);         // 102.4 MB (optional)
    const size_t wb_need = (size_t)2*1024*1024 + (size_t)C_CLS * D_DIM * 2;
    const bool use_wb = ws_size >= wb_need;

    prep_x<<<dim3(B_ROWS), dim3(64), 0, stream>>>(x, XB, SUM);

    const dim3 ggrid(B_ROWS / 256, (C_CLS + 127) / 128);  // (4, 782), M fastest
    if (use_wb) {
        prep_w<true><<<dim3(C_CLS / 4), dim3(256), 0, stream>>>(w, WB, invnw);
        gemm_k<true><<<ggrid, dim3(512), 0, stream>>>(XB, WB, nullptr, nullptr, out, SUM);
    } else {
        prep_w<false><<<dim3(C_CLS / 4), dim3(256), 0, stream>>>(w, WB, invnw);
        gemm_k<false><<<ggrid, dim3(512), 0, stream>>>(XB, nullptr, w, invnw, out, SUM);
    }
    loss_k<<<dim3(1), dim3(1024), 0, stream>>>(out, label, SUM, out);
}